// Round 16
// baseline (161.351 us; speedup 1.0000x reference)
//
#include <hip/hip_runtime.h>
#include <hip/hip_bf16.h>

// GIPAConv: N=50000 nodes, E=800000 edges, F_NODE=128, F_EDGE=8, H_ATT=64, H=8, P=16
#define NODECAP 48       // per-node edge cap (deg ~ Poisson(16); passed r2-r15)
#define NPB 256          // nodes per coarse bucket (partition granularity)
#define BCAP 4608        // edges per region (mean 4082 -> +8 sigma)
#define MAXBUCK 256      // LDS bound (nbuck = 196)
#define PART_CHUNK 1600  // edges per partition block (500 blocks -> ~98K global atomics)
#define SLICES 8         // 32-node agg slices
#define GRIDPAD 200      // agg grid pad: 200 % 8 == 0 -> all slices of a bucket on one XCD
#define PACKB 192        // prep role-A blocks (weight packing)

typedef __attribute__((ext_vector_type(8))) short bf16x8;
typedef __attribute__((ext_vector_type(4))) float f32x4;

static __device__ __forceinline__ short f2b(float f) {
    __hip_bfloat16 h = __float2bfloat16(f);
    return *reinterpret_cast<short*>(&h);
}
static __device__ __forceinline__ float b2f(unsigned short u) {
    union { unsigned int i; float f; } v; v.i = ((unsigned int)u) << 16; return v.f;
}

// Light-roles-only prep (r15 lesson: fusing light roles with the heavy node kernel
// strangles them via the per-kernel resource footprint; light+light is safe, r13):
//   blocks [0, PACKB):             pack weights -> bf16 [col][k]
//   blocks [PACKB, PACKB+partB):   partition edges (LDS histogram -> ~98K block atomics)
//   blocks [PACKB+partB, ...):     pure a_edge MLP -> ae bf16 (no a_src dependency;
//                                  the a_src add happens in bucket_agg)
// gcnt zeroed by hipMemsetAsync before launch.
__global__ __launch_bounds__(256) void prep(
    const float* __restrict__ w_ps, const float* __restrict__ w_pd,
    const float* __restrict__ w_as0, const float* __restrict__ w_ad0,
    short* __restrict__ wp, short* __restrict__ wa,
    const int* __restrict__ src, const int* __restrict__ dst,
    const float* __restrict__ feat_edge,
    const float* __restrict__ w_e0, const float* __restrict__ w_e1,
    int* __restrict__ gcnt, int2* __restrict__ part, short* __restrict__ ae,
    int E, int nbuck, int partB)
{
    __shared__ int smraw[2 * MAXBUCK + PART_CHUNK];
    const int t = threadIdx.x;

    if (blockIdx.x < PACKB) {
        const int idx = blockIdx.x * 256 + t;
        if (idx < 256 * 128) {
            const int c = idx >> 7, k = idx & 127;
            const float v = (c < 128) ? w_ps[(size_t)k * 128 + c] : w_pd[(size_t)k * 128 + (c - 128)];
            wp[idx] = f2b(v);
        } else if (idx < 256 * 128 + 128 * 128) {
            const int j = idx - 256 * 128;
            const int c = j >> 7, k = j & 127;
            const float v = (c < 64) ? w_as0[(size_t)k * 64 + c] : w_ad0[(size_t)k * 64 + (c - 64)];
            wa[j] = f2b(v);
        }
        return;
    }

    if (blockIdx.x < PACKB + partB) {
        // ---- partition role ----
        int* hist   = smraw;
        int* cursor = hist + MAXBUCK;
        int* dcache = cursor + MAXBUCK;
        const int e0 = (blockIdx.x - PACKB) * PART_CHUNK;
        const int e1 = min(e0 + PART_CHUNK, E);

        for (int i = t; i < nbuck; i += 256) hist[i] = 0;
        __syncthreads();
        for (int e = e0 + t; e < e1; e += 256) {
            const int d = dst[e];
            dcache[e - e0] = d;
            atomicAdd(&hist[d >> 8], 1);
        }
        __syncthreads();
        for (int i = t; i < nbuck; i += 256) {
            const int c = hist[i];
            cursor[i] = (c > 0) ? atomicAdd(&gcnt[i], c) : 0;
        }
        __syncthreads();
        for (int e = e0 + t; e < e1; e += 256) {
            const int d = dcache[e - e0];
            const int s = src[e];
            const int b = d >> 8;
            const int pos = atomicAdd(&cursor[b], 1);
            if (pos < BCAP)
                part[(size_t)b * BCAP + pos] = make_int2((e << 8) | (d & 255), s);
        }
        return;
    }

    // ---- pure a_edge MLP role (atomic-free, gather-free stream) ----
    const int e = (blockIdx.x - PACKB - partB) * 256 + t;
    if (e >= E) return;
    float fe[8];
    const float4 v0 = *reinterpret_cast<const float4*>(feat_edge + (size_t)e * 8);
    const float4 v1 = *reinterpret_cast<const float4*>(feat_edge + (size_t)e * 8 + 4);
    fe[0] = v0.x; fe[1] = v0.y; fe[2] = v0.z; fe[3] = v0.w;
    fe[4] = v1.x; fe[5] = v1.y; fe[6] = v1.z; fe[7] = v1.w;
    float av[8] = {};
    #pragma unroll 8
    for (int j = 0; j < 64; ++j) {
        float hj = 0.f;
        #pragma unroll
        for (int k = 0; k < 8; ++k) hj += fe[k] * w_e0[k * 64 + j];
        hj = fmaxf(hj, 0.f);
        #pragma unroll
        for (int hh = 0; hh < 8; ++hh) av[hh] += hj * w_e1[j * 8 + hh];
    }
    short eb[8];
    #pragma unroll
    for (int hh = 0; hh < 8; ++hh) eb[hh] = f2b(av[hh]);
    *reinterpret_cast<uint4*>(ae + (size_t)e * 8) = *reinterpret_cast<const uint4*>(eb);
}

// 64 nodes per block, 4 waves. MFMA 16x16x32 bf16. Emits prop_bf + pd_bf (bf16),
// a_src (bf16), a_dst (f32). Standalone heavy kernel (r5/r7/r15: never fuse light roles in).
__global__ __launch_bounds__(256) void node_mfma(
    const float* __restrict__ feat,
    const short* __restrict__ wp, const short* __restrict__ wa,
    const float* __restrict__ b_ps, const float* __restrict__ b_pd,
    const float* __restrict__ w_as1, const float* __restrict__ w_ad1,
    short* __restrict__ prop_bf, short* __restrict__ pd_bf,
    short* __restrict__ a_src_bf, float* __restrict__ a_dst, int n)
{
    __shared__ unsigned char afb[64 * 256];   // 64 rows x 128 bf16, XOR-swizzled (T2)
    __shared__ short ht[64][137];             // relu hidden (bf16), padded stride
    const int t = threadIdx.x;
    const int lane = t & 63;
    const int wid = t >> 6;                   // wave 0..3
    const int l15 = lane & 15;
    const int l4 = lane >> 4;                 // 0..3
    const int base = blockIdx.x * 64;

    // ---- stage feat (f32) -> bf16 LDS, swizzled ----
    #pragma unroll
    for (int i = 0; i < 4; ++i) {
        const int chunk = t + i * 256;
        const int row = chunk >> 4;
        const int kc = chunk & 15;
        const int grow = base + row;
        float f[8];
        if (grow < n) {
            const float4 v0 = *reinterpret_cast<const float4*>(feat + (size_t)grow * 128 + kc * 8);
            const float4 v1 = *reinterpret_cast<const float4*>(feat + (size_t)grow * 128 + kc * 8 + 4);
            f[0] = v0.x; f[1] = v0.y; f[2] = v0.z; f[3] = v0.w;
            f[4] = v1.x; f[5] = v1.y; f[6] = v1.z; f[7] = v1.w;
        } else {
            #pragma unroll
            for (int j = 0; j < 8; ++j) f[j] = 0.f;
        }
        short h8[8];
        #pragma unroll
        for (int j = 0; j < 8; ++j) h8[j] = f2b(f[j]);
        const int byte = (row * 256 + kc * 16) ^ ((row & 7) << 4);
        *reinterpret_cast<bf16x8*>(afb + byte) = *reinterpret_cast<const bf16x8*>(h8);
    }
    __syncthreads();

    // ---- prop = feat @ [w_ps|w_pd] ----
    {
        f32x4 acc[4][4] = {};
        for (int kk = 0; kk < 4; ++kk) {
            bf16x8 a[4], b[4];
            #pragma unroll
            for (int rt = 0; rt < 4; ++rt) {
                const int arow = rt * 16 + l15;
                const int ab = (arow * 256 + kk * 64 + l4 * 16) ^ ((arow & 7) << 4);
                a[rt] = *reinterpret_cast<const bf16x8*>(afb + ab);
            }
            #pragma unroll
            for (int c = 0; c < 4; ++c) {
                const int col = (wid * 4 + c) * 16 + l15;
                b[c] = *reinterpret_cast<const bf16x8*>(wp + (size_t)col * 128 + kk * 32 + l4 * 8);
            }
            #pragma unroll
            for (int rt = 0; rt < 4; ++rt)
                #pragma unroll
                for (int c = 0; c < 4; ++c)
                    acc[rt][c] = __builtin_amdgcn_mfma_f32_16x16x32_bf16(a[rt], b[c], acc[rt][c], 0, 0, 0);
        }
        #pragma unroll
        for (int c = 0; c < 4; ++c) {
            const int col = (wid * 4 + c) * 16 + l15;
            const bool sr = (col < 128);
            const float bias = sr ? b_ps[col] : b_pd[col - 128];
            short* dbase = sr ? (prop_bf + col) : (pd_bf + (col - 128));
            #pragma unroll
            for (int rt = 0; rt < 4; ++rt)
                #pragma unroll
                for (int r = 0; r < 4; ++r) {
                    const int row = base + rt * 16 + l4 * 4 + r;
                    if (row < n) dbase[(size_t)row * 128] = f2b(acc[rt][c][r] + bias);
                }
        }
    }

    // ---- hidden = relu(feat @ [w_as0|w_ad0]) ----
    {
        f32x4 acc[4][2] = {};
        for (int kk = 0; kk < 4; ++kk) {
            bf16x8 a[4], b[2];
            #pragma unroll
            for (int rt = 0; rt < 4; ++rt) {
                const int arow = rt * 16 + l15;
                const int ab = (arow * 256 + kk * 64 + l4 * 16) ^ ((arow & 7) << 4);
                a[rt] = *reinterpret_cast<const bf16x8*>(afb + ab);
            }
            #pragma unroll
            for (int c = 0; c < 2; ++c) {
                const int col = (wid * 2 + c) * 16 + l15;
                b[c] = *reinterpret_cast<const bf16x8*>(wa + (size_t)col * 128 + kk * 32 + l4 * 8);
            }
            #pragma unroll
            for (int rt = 0; rt < 4; ++rt)
                #pragma unroll
                for (int c = 0; c < 2; ++c)
                    acc[rt][c] = __builtin_amdgcn_mfma_f32_16x16x32_bf16(a[rt], b[c], acc[rt][c], 0, 0, 0);
        }
        #pragma unroll
        for (int c = 0; c < 2; ++c) {
            const int col = (wid * 2 + c) * 16 + l15;
            #pragma unroll
            for (int rt = 0; rt < 4; ++rt)
                #pragma unroll
                for (int r = 0; r < 4; ++r)
                    ht[rt * 16 + l4 * 4 + r][col] = f2b(fmaxf(acc[rt][c][r], 0.f));
        }
    }
    __syncthreads();

    // ---- phase 3: a_src (bf16) / a_dst (f32) = hidden @ w1 ----
    #pragma unroll
    for (int o = 0; o < 4; ++o) {
        const int idx = t + o * 256;
        const int i = idx >> 4;
        const int hh = idx & 15;
        const bool is_src = (hh < 8);
        const int h = is_src ? hh : (hh - 8);
        const float* w1 = is_src ? w_as1 : w_ad1;
        const int jb = is_src ? 0 : 64;
        float acc = 0.f;
        #pragma unroll
        for (int j = 0; j < 64; ++j)
            acc += b2f((unsigned short)ht[i][jb + j]) * w1[j * 8 + h];
        const int row = base + i;
        if (row < n) {
            if (is_src) a_src_bf[(size_t)row * 8 + h] = f2b(acc);
            else        a_dst[(size_t)row * 8 + h] = acc;
        }
    }
}

// Block = one 32-node slice of a 256-node coarse bucket. Grid is PADDED to
// GRIDPAD(=200, ≡0 mod 8) buckets and TRANSPOSED (bucket = bid % GRIDPAD) so all 8
// slices of a bucket land on the SAME XCD under round-robin dispatch -> the shared
// ~36KB part-region is fetched from HBM once per bucket, not 8x (r13/r14: the scan
// was ~100 MB of redundant HBM traffic).
// Per-node gather core with 8-deep batching: ex = expf(relu(ae[e]+a_src[s]+a_dst[node])),
// prop row gather, in-loop denominator, out = pd_bf + agg (single write).
__global__ __launch_bounds__(256) void bucket_agg(
    const int2* __restrict__ part, const int* __restrict__ gcnt,
    const short* __restrict__ ae, const short* __restrict__ a_src_bf,
    const float* __restrict__ a_dst,
    const short* __restrict__ prop_bf, const short* __restrict__ pd_bf,
    float* __restrict__ out, int n, int nbuck)
{
    __shared__ int2  lists[32][NODECAP];  // (e, s)  12 KB
    __shared__ int   lcnt[32];
    __shared__ float adst_s[32][8];       // 1 KB
    const int t = threadIdx.x;
    const int b = blockIdx.x % GRIDPAD;   // coarse bucket (transposed grid)
    const int slice = blockIdx.x / GRIDPAD;
    if (b >= nbuck) return;
    const int node0 = (b << 8) + (slice << 5);

    if (t < 32) lcnt[t] = 0;
    {
        const int r = t >> 3, h = t & 7;  // t covers 32*8 = 256 exactly
        const int nd = node0 + r;
        adst_s[r][h] = (nd < n) ? a_dst[(size_t)nd * 8 + h] : 0.f;
    }
    __syncthreads();

    const int cnt = min(gcnt[b], BCAP);
    const int2* pb = part + (size_t)b * BCAP;
    for (int j = t; j < cnt; j += 256) {
        const int2 pr = pb[j];
        const int dlow = pr.x & 255;
        if ((dlow >> 5) == slice) {
            const int r = dlow & 31;
            const int slot = atomicAdd(&lcnt[r], 1);
            if (slot < NODECAP) lists[r][slot] = make_int2(pr.x >> 8, pr.y); // (e, s)
        }
    }
    __syncthreads();

    const int grp = t >> 5, l = t & 31;   // 8 groups of 32 lanes
    const int h = l >> 2, q = l & 3;

    for (int r = grp; r < 32; r += 8) {
        const int node = node0 + r;
        if (node >= n) continue;
        int deg = lcnt[r];
        if (deg > NODECAP) deg = NODECAP;
        const float adv = adst_s[r][h];

        float dsumv = 0.f;
        float4 acc = make_float4(0.f, 0.f, 0.f, 0.f);
        for (int j0 = 0; j0 < deg; j0 += 8) {
            float at[8]; float4 pv[8];
            #pragma unroll
            for (int u = 0; u < 8; ++u) {
                const int j = j0 + u;
                const bool act = (j < deg);
                const int2 pr = lists[r][act ? j : 0];   // LDS broadcast across group
                at[u] = b2f((unsigned short)ae[(size_t)pr.x * 8 + h])
                      + b2f((unsigned short)a_src_bf[(size_t)pr.y * 8 + h]);
                const ushort4 p = *reinterpret_cast<const ushort4*>(
                    prop_bf + (size_t)pr.y * 128 + h * 16 + q * 4);
                pv[u] = make_float4(b2f(p.x), b2f(p.y), b2f(p.z), b2f(p.w));
            }
            #pragma unroll
            for (int u = 0; u < 8; ++u) {
                const bool act = (j0 + u < deg);
                const float ex = act ? __expf(fmaxf(at[u] + adv, 0.f)) : 0.f;
                dsumv += ex;
                acc.x += ex * pv[u].x; acc.y += ex * pv[u].y;
                acc.z += ex * pv[u].z; acc.w += ex * pv[u].w;
            }
        }
        const float dinv = 1.f / fmaxf(dsumv, 1e-16f);

        // out = prop_dst residual (bf16) + aggregated messages  (single write, no RMW)
        const ushort4 pd = *reinterpret_cast<const ushort4*>(
            pd_bf + (size_t)node * 128 + h * 16 + q * 4);
        float4 o;
        o.x = b2f(pd.x) + acc.x * dinv; o.y = b2f(pd.y) + acc.y * dinv;
        o.z = b2f(pd.z) + acc.z * dinv; o.w = b2f(pd.w) + acc.w * dinv;
        *reinterpret_cast<float4*>(out + (size_t)node * 128 + h * 16 + q * 4) = o;
    }
}

extern "C" void kernel_launch(void* const* d_in, const int* in_sizes, int n_in,
                              void* d_out, int out_size, void* d_ws, size_t ws_size,
                              hipStream_t stream)
{
    const float* feat      = (const float*)d_in[0];
    const float* feat_edge = (const float*)d_in[1];
    const int*   src       = (const int*)d_in[2];
    const int*   dst       = (const int*)d_in[3];
    const float* w_as0     = (const float*)d_in[4];
    const float* w_as1     = (const float*)d_in[5];
    const float* w_ad0     = (const float*)d_in[6];
    const float* w_ad1     = (const float*)d_in[7];
    const float* w_e0      = (const float*)d_in[8];
    const float* w_e1      = (const float*)d_in[9];
    const float* w_ps      = (const float*)d_in[10];
    const float* b_ps      = (const float*)d_in[11];
    const float* w_pd      = (const float*)d_in[12];
    const float* b_pd      = (const float*)d_in[13];

    const int n = in_sizes[0] / 128;   // 50000
    const int E = in_sizes[2];         // 800000
    const int nbuck = (n + NPB - 1) / NPB;   // 196
    float* out = (float*)d_out;

    // workspace layout (~48 MB):
    //   prop_bf[n*128] bf16 | pd_bf[n*128] bf16 | a_src_bf[n*8] bf16 | a_dst[n*8] f32 |
    //   gcnt[nbuck] i32 | part[nbuck*BCAP] int2 | ae[E*8] bf16 | wp[256*128] | wa[128*128]
    short* prop_bf = (short*)d_ws;
    short* pd_bf   = prop_bf + (size_t)n * 128;
    short* a_src_bf = pd_bf + (size_t)n * 128;
    float* a_dst = (float*)(a_src_bf + (size_t)n * 8);
    int*   gcnt  = (int*)(a_dst + (size_t)n * 8);
    int2*  part  = (int2*)(gcnt + ((nbuck + 1) & ~1));
    short* ae    = (short*)(part + (size_t)nbuck * BCAP);
    short* wp    = ae + (size_t)E * 8;
    short* wa    = wp + 256 * 128;

    hipMemsetAsync(gcnt, 0, (size_t)nbuck * sizeof(int), stream);

    const int partB = (E + PART_CHUNK - 1) / PART_CHUNK;  // 500
    const int aeB   = (E + 255) / 256;                    // 3125
    prep<<<PACKB + partB + aeB, 256, 0, stream>>>(
        w_ps, w_pd, w_as0, w_ad0, wp, wa,
        src, dst, feat_edge, w_e0, w_e1,
        gcnt, part, ae, E, nbuck, partB);

    node_mfma<<<(n + 63) / 64, 256, 0, stream>>>(
        feat, wp, wa, b_ps, b_pd, w_as1, w_ad1,
        prop_bf, pd_bf, a_src_bf, a_dst, n);

    bucket_agg<<<GRIDPAD * SLICES, 256, 0, stream>>>(
        part, gcnt, ae, a_src_bf, a_dst, prop_bf, pd_bf, out, n, nbuck);
}

// Round 18
// 148.741 us; speedup vs baseline: 1.0848x; 1.0848x over previous
//
#include <hip/hip_runtime.h>
#include <hip/hip_bf16.h>

// GIPAConv: N=50000 nodes, E=800000 edges, F_NODE=128, F_EDGE=8, H_ATT=64, H=8, P=16
#define NODECAP 48       // per-node edge cap (deg ~ Poisson(16); passed r2-r16)
#define NPB 256          // nodes per coarse bucket (partition granularity)
#define BCAP 4608        // edges per region (mean 4082 -> +8 sigma)
#define MAXBUCK 256      // LDS bound (nbuck = 196)
#define PART_CHUNK 1600  // edges per partition block (500 blocks -> ~98K global atomics)
#define EPART_BLOCKS 500 // role-split: first 500 blocks of edge_part partition
#define SLICES 8         // 32-node agg slices (r14 optimum; r16's grid transpose reverted)

typedef __attribute__((ext_vector_type(8))) short bf16x8;
typedef __attribute__((ext_vector_type(4))) float f32x4;

static __device__ __forceinline__ short f2b(float f) {
    __hip_bfloat16 h = __float2bfloat16(f);
    return *reinterpret_cast<short*>(&h);
}
static __device__ __forceinline__ float b2f(unsigned short u) {
    union { unsigned int i; float f; } v; v.i = ((unsigned int)u) << 16; return v.f;
}

// pack weights to bf16 [col][k] B-fragment layout; also zero gcnt[nbuck]
__global__ __launch_bounds__(256) void pack_w(
    const float* __restrict__ w_ps, const float* __restrict__ w_pd,
    const float* __restrict__ w_as0, const float* __restrict__ w_ad0,
    short* __restrict__ wp, short* __restrict__ wa, int* __restrict__ gcnt, int nbuck)
{
    const int idx = blockIdx.x * 256 + threadIdx.x;
    if (idx < 256 * 128) {
        const int c = idx >> 7, k = idx & 127;
        const float v = (c < 128) ? w_ps[(size_t)k * 128 + c] : w_pd[(size_t)k * 128 + (c - 128)];
        wp[idx] = f2b(v);
    } else if (idx < 256 * 128 + 128 * 128) {
        const int j = idx - 256 * 128;
        const int c = j >> 7, k = j & 127;
        const float v = (c < 64) ? w_as0[(size_t)k * 64 + c] : w_ad0[(size_t)k * 64 + (c - 64)];
        wa[j] = f2b(v);
    }
    if (idx < nbuck) gcnt[idx] = 0;
}

// 64 nodes per block, 4 waves. MFMA 16x16x32 bf16. Emits prop_bf + pd_bf (bf16),
// a_src (bf16), a_dst (f32). Standalone heavy kernel (r5/r7/r15: never fuse light roles in).
__global__ __launch_bounds__(256) void node_mfma(
    const float* __restrict__ feat,
    const short* __restrict__ wp, const short* __restrict__ wa,
    const float* __restrict__ b_ps, const float* __restrict__ b_pd,
    const float* __restrict__ w_as1, const float* __restrict__ w_ad1,
    short* __restrict__ prop_bf, short* __restrict__ pd_bf,
    short* __restrict__ a_src_bf, float* __restrict__ a_dst, int n)
{
    __shared__ unsigned char afb[64 * 256];   // 64 rows x 128 bf16, XOR-swizzled (T2)
    __shared__ short ht[64][137];             // relu hidden (bf16), padded stride
    const int t = threadIdx.x;
    const int lane = t & 63;
    const int wid = t >> 6;                   // wave 0..3
    const int l15 = lane & 15;
    const int l4 = lane >> 4;                 // 0..3
    const int base = blockIdx.x * 64;

    // ---- stage feat (f32) -> bf16 LDS, swizzled ----
    #pragma unroll
    for (int i = 0; i < 4; ++i) {
        const int chunk = t + i * 256;
        const int row = chunk >> 4;
        const int kc = chunk & 15;
        const int grow = base + row;
        float f[8];
        if (grow < n) {
            const float4 v0 = *reinterpret_cast<const float4*>(feat + (size_t)grow * 128 + kc * 8);
            const float4 v1 = *reinterpret_cast<const float4*>(feat + (size_t)grow * 128 + kc * 8 + 4);
            f[0] = v0.x; f[1] = v0.y; f[2] = v0.z; f[3] = v0.w;
            f[4] = v1.x; f[5] = v1.y; f[6] = v1.z; f[7] = v1.w;
        } else {
            #pragma unroll
            for (int j = 0; j < 8; ++j) f[j] = 0.f;
        }
        short h8[8];
        #pragma unroll
        for (int j = 0; j < 8; ++j) h8[j] = f2b(f[j]);
        const int byte = (row * 256 + kc * 16) ^ ((row & 7) << 4);
        *reinterpret_cast<bf16x8*>(afb + byte) = *reinterpret_cast<const bf16x8*>(h8);
    }
    __syncthreads();

    // ---- prop = feat @ [w_ps|w_pd] ----
    {
        f32x4 acc[4][4] = {};
        for (int kk = 0; kk < 4; ++kk) {
            bf16x8 a[4], b[4];
            #pragma unroll
            for (int rt = 0; rt < 4; ++rt) {
                const int arow = rt * 16 + l15;
                const int ab = (arow * 256 + kk * 64 + l4 * 16) ^ ((arow & 7) << 4);
                a[rt] = *reinterpret_cast<const bf16x8*>(afb + ab);
            }
            #pragma unroll
            for (int c = 0; c < 4; ++c) {
                const int col = (wid * 4 + c) * 16 + l15;
                b[c] = *reinterpret_cast<const bf16x8*>(wp + (size_t)col * 128 + kk * 32 + l4 * 8);
            }
            #pragma unroll
            for (int rt = 0; rt < 4; ++rt)
                #pragma unroll
                for (int c = 0; c < 4; ++c)
                    acc[rt][c] = __builtin_amdgcn_mfma_f32_16x16x32_bf16(a[rt], b[c], acc[rt][c], 0, 0, 0);
        }
        #pragma unroll
        for (int c = 0; c < 4; ++c) {
            const int col = (wid * 4 + c) * 16 + l15;
            const bool sr = (col < 128);
            const float bias = sr ? b_ps[col] : b_pd[col - 128];
            short* dbase = sr ? (prop_bf + col) : (pd_bf + (col - 128));
            #pragma unroll
            for (int rt = 0; rt < 4; ++rt)
                #pragma unroll
                for (int r = 0; r < 4; ++r) {
                    const int row = base + rt * 16 + l4 * 4 + r;
                    if (row < n) dbase[(size_t)row * 128] = f2b(acc[rt][c][r] + bias);
                }
        }
    }

    // ---- hidden = relu(feat @ [w_as0|w_ad0]) ----
    {
        f32x4 acc[4][2] = {};
        for (int kk = 0; kk < 4; ++kk) {
            bf16x8 a[4], b[2];
            #pragma unroll
            for (int rt = 0; rt < 4; ++rt) {
                const int arow = rt * 16 + l15;
                const int ab = (arow * 256 + kk * 64 + l4 * 16) ^ ((arow & 7) << 4);
                a[rt] = *reinterpret_cast<const bf16x8*>(afb + ab);
            }
            #pragma unroll
            for (int c = 0; c < 2; ++c) {
                const int col = (wid * 2 + c) * 16 + l15;
                b[c] = *reinterpret_cast<const bf16x8*>(wa + (size_t)col * 128 + kk * 32 + l4 * 8);
            }
            #pragma unroll
            for (int rt = 0; rt < 4; ++rt)
                #pragma unroll
                for (int c = 0; c < 2; ++c)
                    acc[rt][c] = __builtin_amdgcn_mfma_f32_16x16x32_bf16(a[rt], b[c], acc[rt][c], 0, 0, 0);
        }
        #pragma unroll
        for (int c = 0; c < 2; ++c) {
            const int col = (wid * 2 + c) * 16 + l15;
            #pragma unroll
            for (int rt = 0; rt < 4; ++rt)
                #pragma unroll
                for (int r = 0; r < 4; ++r)
                    ht[rt * 16 + l4 * 4 + r][col] = f2b(fmaxf(acc[rt][c][r], 0.f));
        }
    }
    __syncthreads();

    // ---- phase 3: a_src (bf16) / a_dst (f32) = hidden @ w1 ----
    #pragma unroll
    for (int o = 0; o < 4; ++o) {
        const int idx = t + o * 256;
        const int i = idx >> 4;
        const int hh = idx & 15;
        const bool is_src = (hh < 8);
        const int h = is_src ? hh : (hh - 8);
        const float* w1 = is_src ? w_as1 : w_ad1;
        const int jb = is_src ? 0 : 64;
        float acc = 0.f;
        #pragma unroll
        for (int j = 0; j < 64; ++j)
            acc += b2f((unsigned short)ht[i][jb + j]) * w1[j * 8 + h];
        const int row = base + i;
        if (row < n) {
            if (is_src) a_src_bf[(size_t)row * 8 + h] = f2b(acc);
            else        a_dst[(size_t)row * 8 + h] = acc;
        }
    }
}

// Role-split edge kernel. Blocks [0, EPART_BLOCKS): partition (LDS histogram -> one
// global atomic per (block,bucket), ~98K total -> LDS-cursor scatter). Blocks
// [EPART_BLOCKS, ...): per-edge MLP + a_src gather -> ax (bf16). Both stream the edge
// list; partition's atomics hide under the MLP blocks' compute on other CUs.
__global__ __launch_bounds__(256) void edge_part(
    const int* __restrict__ src, const int* __restrict__ dst,
    const float* __restrict__ feat_edge,
    const float* __restrict__ w_e0, const float* __restrict__ w_e1,
    const short* __restrict__ a_src_bf,
    int* __restrict__ gcnt, int2* __restrict__ part, short* __restrict__ ax,
    int E, int nbuck)
{
    __shared__ int hist[MAXBUCK];
    __shared__ int cursor[MAXBUCK];
    __shared__ int dcache[PART_CHUNK];
    const int t = threadIdx.x;

    if (blockIdx.x < EPART_BLOCKS) {
        const int e0 = blockIdx.x * PART_CHUNK;
        const int e1 = min(e0 + PART_CHUNK, E);

        for (int i = t; i < nbuck; i += 256) hist[i] = 0;
        __syncthreads();
        for (int e = e0 + t; e < e1; e += 256) {
            const int d = dst[e];
            dcache[e - e0] = d;
            atomicAdd(&hist[d >> 8], 1);
        }
        __syncthreads();
        for (int i = t; i < nbuck; i += 256) {
            const int c = hist[i];
            cursor[i] = (c > 0) ? atomicAdd(&gcnt[i], c) : 0;
        }
        __syncthreads();
        for (int e = e0 + t; e < e1; e += 256) {
            const int d = dcache[e - e0];
            const int s = src[e];
            const int b = d >> 8;
            const int pos = atomicAdd(&cursor[b], 1);
            if (pos < BCAP)
                part[(size_t)b * BCAP + pos] = make_int2((e << 8) | (d & 255), s);
        }
        return;
    }

    const int e = (blockIdx.x - EPART_BLOCKS) * 256 + t;
    if (e >= E) return;

    float fe[8];
    const float4 v0 = *reinterpret_cast<const float4*>(feat_edge + (size_t)e * 8);
    const float4 v1 = *reinterpret_cast<const float4*>(feat_edge + (size_t)e * 8 + 4);
    fe[0] = v0.x; fe[1] = v0.y; fe[2] = v0.z; fe[3] = v0.w;
    fe[4] = v1.x; fe[5] = v1.y; fe[6] = v1.z; fe[7] = v1.w;

    // tiny MLP: weight indices thread-uniform -> scalar loads
    float ae[8] = {};
    #pragma unroll 8
    for (int j = 0; j < 64; ++j) {
        float hj = 0.f;
        #pragma unroll
        for (int k = 0; k < 8; ++k) hj += fe[k] * w_e0[k * 64 + j];
        hj = fmaxf(hj, 0.f);
        #pragma unroll
        for (int hh = 0; hh < 8; ++hh) ae[hh] += hj * w_e1[j * 8 + hh];
    }

    const int s = src[e];
    const ushort4 as0 = *reinterpret_cast<const ushort4*>(a_src_bf + (size_t)s * 8);
    const ushort4 as1 = *reinterpret_cast<const ushort4*>(a_src_bf + (size_t)s * 8 + 4);
    short eb[8];
    eb[0] = f2b(ae[0] + b2f(as0.x)); eb[1] = f2b(ae[1] + b2f(as0.y));
    eb[2] = f2b(ae[2] + b2f(as0.z)); eb[3] = f2b(ae[3] + b2f(as0.w));
    eb[4] = f2b(ae[4] + b2f(as1.x)); eb[5] = f2b(ae[5] + b2f(as1.y));
    eb[6] = f2b(ae[6] + b2f(as1.z)); eb[7] = f2b(ae[7] + b2f(as1.w));
    *reinterpret_cast<uint4*>(ax + (size_t)e * 8) = *reinterpret_cast<const uint4*>(eb);
}

// Block = one 32-node slice of a 256-node coarse bucket, LINEAR grid (b = bid>>3:
// adjacent slice-blocks of a bucket dispatch near-simultaneously and share the region
// scan in L2 — r16's XCD-transpose broke this temporal locality and regressed 57->71us).
// Re-bucket into per-node LDS lists, then per-node gather core with 8-deep batching:
// ex = expf(relu(ax[e] + a_dst[node])), in-loop denominator, out = pd + agg
// (pd prefetched before the loop; nontemporal out store keeps L2 for prop rows).
__global__ __launch_bounds__(256) void bucket_agg(
    const int2* __restrict__ part, const int* __restrict__ gcnt,
    const short* __restrict__ ax, const float* __restrict__ a_dst,
    const short* __restrict__ prop_bf, const short* __restrict__ pd_bf,
    float* __restrict__ out, int n)
{
    __shared__ int2  lists[32][NODECAP];  // (e, s)  12 KB
    __shared__ int   lcnt[32];
    __shared__ float adst_s[32][8];       // 1 KB
    const int t = threadIdx.x;
    const int b = blockIdx.x >> 3;        // coarse bucket
    const int slice = blockIdx.x & 7;     // 32-node slice
    const int node0 = (b << 8) + (slice << 5);

    if (t < 32) lcnt[t] = 0;
    {
        const int r = t >> 3, h = t & 7;  // t covers 32*8 = 256 exactly
        const int nd = node0 + r;
        adst_s[r][h] = (nd < n) ? a_dst[(size_t)nd * 8 + h] : 0.f;
    }
    __syncthreads();

    const int cnt = min(gcnt[b], BCAP);
    const int2* pb = part + (size_t)b * BCAP;
    for (int j = t; j < cnt; j += 256) {
        const int2 pr = pb[j];
        const int dlow = pr.x & 255;
        if ((dlow >> 5) == slice) {
            const int r = dlow & 31;
            const int slot = atomicAdd(&lcnt[r], 1);
            if (slot < NODECAP) lists[r][slot] = make_int2(pr.x >> 8, pr.y); // (e, s)
        }
    }
    __syncthreads();

    const int grp = t >> 5, l = t & 31;   // 8 groups of 32 lanes
    const int h = l >> 2, q = l & 3;

    for (int r = grp; r < 32; r += 8) {
        const int node = node0 + r;
        if (node >= n) continue;
        int deg = lcnt[r];
        if (deg > NODECAP) deg = NODECAP;
        const float adv = adst_s[r][h];

        // prefetch the residual early: its latency hides under the gather loop below
        const ushort4 pd = *reinterpret_cast<const ushort4*>(
            pd_bf + (size_t)node * 128 + h * 16 + q * 4);

        float dsumv = 0.f;
        float4 acc = make_float4(0.f, 0.f, 0.f, 0.f);
        for (int j0 = 0; j0 < deg; j0 += 8) {
            float at[8]; float4 pv[8];
            #pragma unroll
            for (int u = 0; u < 8; ++u) {
                const int j = j0 + u;
                const bool act = (j < deg);
                const int2 pr = lists[r][act ? j : 0];   // LDS broadcast across group
                at[u] = b2f((unsigned short)ax[(size_t)pr.x * 8 + h]);
                const ushort4 p = *reinterpret_cast<const ushort4*>(
                    prop_bf + (size_t)pr.y * 128 + h * 16 + q * 4);
                pv[u] = make_float4(b2f(p.x), b2f(p.y), b2f(p.z), b2f(p.w));
            }
            #pragma unroll
            for (int u = 0; u < 8; ++u) {
                const bool act = (j0 + u < deg);
                const float ex = act ? __expf(fmaxf(at[u] + adv, 0.f)) : 0.f;
                dsumv += ex;
                acc.x += ex * pv[u].x; acc.y += ex * pv[u].y;
                acc.z += ex * pv[u].z; acc.w += ex * pv[u].w;
            }
        }
        const float dinv = 1.f / fmaxf(dsumv, 1e-16f);

        f32x4 o;
        o[0] = b2f(pd.x) + acc.x * dinv; o[1] = b2f(pd.y) + acc.y * dinv;
        o[2] = b2f(pd.z) + acc.z * dinv; o[3] = b2f(pd.w) + acc.w * dinv;
        // nontemporal: out is written once, never re-read — keep L2 for prop_bf
        // (f32x4 is a clang ext_vector_type; HIP's float4 struct is rejected by the builtin)
        __builtin_nontemporal_store(o, reinterpret_cast<f32x4*>(
            out + (size_t)node * 128 + h * 16 + q * 4));
    }
}

extern "C" void kernel_launch(void* const* d_in, const int* in_sizes, int n_in,
                              void* d_out, int out_size, void* d_ws, size_t ws_size,
                              hipStream_t stream)
{
    const float* feat      = (const float*)d_in[0];
    const float* feat_edge = (const float*)d_in[1];
    const int*   src       = (const int*)d_in[2];
    const int*   dst       = (const int*)d_in[3];
    const float* w_as0     = (const float*)d_in[4];
    const float* w_as1     = (const float*)d_in[5];
    const float* w_ad0     = (const float*)d_in[6];
    const float* w_ad1     = (const float*)d_in[7];
    const float* w_e0      = (const float*)d_in[8];
    const float* w_e1      = (const float*)d_in[9];
    const float* w_ps      = (const float*)d_in[10];
    const float* b_ps      = (const float*)d_in[11];
    const float* w_pd      = (const float*)d_in[12];
    const float* b_pd      = (const float*)d_in[13];

    const int n = in_sizes[0] / 128;   // 50000
    const int E = in_sizes[2];         // 800000
    const int nbuck = (n + NPB - 1) / NPB;   // 196
    float* out = (float*)d_out;

    // workspace layout (~48 MB):
    //   prop_bf[n*128] bf16 | pd_bf[n*128] bf16 | a_src_bf[n*8] bf16 | a_dst[n*8] f32 |
    //   gcnt[nbuck] i32 | part[nbuck*BCAP] int2 | ax[E*8] bf16 | wp[256*128] | wa[128*128]
    short* prop_bf = (short*)d_ws;
    short* pd_bf   = prop_bf + (size_t)n * 128;
    short* a_src_bf = pd_bf + (size_t)n * 128;
    float* a_dst = (float*)(a_src_bf + (size_t)n * 8);
    int*   gcnt  = (int*)(a_dst + (size_t)n * 8);
    int2*  part  = (int2*)(gcnt + ((nbuck + 1) & ~1));
    short* ax    = (short*)(part + (size_t)nbuck * BCAP);
    short* wp    = ax + (size_t)E * 8;
    short* wa    = wp + 256 * 128;

    pack_w<<<192, 256, 0, stream>>>(
        w_ps, w_pd, w_as0, w_ad0, wp, wa, gcnt, nbuck);

    node_mfma<<<(n + 63) / 64, 256, 0, stream>>>(
        feat, wp, wa, b_ps, b_pd, w_as1, w_ad1,
        prop_bf, pd_bf, a_src_bf, a_dst, n);

    const int axBlocks = (E + 255) / 256;   // 3125
    edge_part<<<EPART_BLOCKS + axBlocks, 256, 0, stream>>>(
        src, dst, feat_edge, w_e0, w_e1, a_src_bf, gcnt, part, ax, E, nbuck);

    bucket_agg<<<nbuck * SLICES, 256, 0, stream>>>(
        part, gcnt, ax, a_dst, prop_bf, pd_bf, out, n);
}